// Round 3
// baseline (7170.965 us; speedup 1.0000x reference)
//
#include <hip/hip_runtime.h>
#include <hip/hip_bf16.h>
#include <math.h>

// ---------------- problem constants ----------------
static constexpr int HIDN = 256;
static constexpr int NWPAD = 240;          // padded window-time steps (240 % {1,3,6,12} == 0)
// out offsets (in floats)
static constexpr size_t NET_OFF  = 0;                  // 211*256*18
static constexpr size_t WOUT_OFF = 972288;             // 211*256*18
static constexpr size_t HO_OFF   = 1944576;            // 256*18
static constexpr size_t VAL_OFF  = 1949184;            // 256*18
static constexpr size_t PEN_OFF  = 1953792;             // 1
// ws offsets (bytes)
static constexpr size_t OFF_LEVS = 0;                  // 256*240*4
static constexpr size_t OFF_SEAS = 245760;             // 256*264*4
static constexpr size_t OFF_X0   = 516096;             // 61440*32*2
static constexpr size_t OFF_Y1   = 4448256;            // 61440*256*2
static constexpr size_t OFF_Y2   = 35905536;
static constexpr size_t OFF_Y3   = 67362816;
static constexpr size_t OFF_W0   = 98820096;           // 9*64*64*8*2
static constexpr size_t OFF_W1   = 99409920;           // 16*64*64*8*2
static constexpr size_t OFF_W2   = 100458496;
static constexpr size_t OFF_W3   = 101507072;
static constexpr size_t OFF_WNL  = 102555648;          // 8*16*64*8*2
static constexpr size_t OFF_WSC  = 102686720;          // 8*2*64*8*2

typedef __attribute__((ext_vector_type(8))) short bf16x8;
typedef __attribute__((ext_vector_type(4))) float f32x4;

__device__ __forceinline__ unsigned short f2bf(float f) {
  unsigned int u = __float_as_uint(f);
  unsigned int r = (u + 0x7FFFu + ((u >> 16) & 1u)) >> 16;
  return (unsigned short)r;
}
__device__ __forceinline__ float bf2f(unsigned short s) {
  return __uint_as_float(((unsigned int)s) << 16);
}
__device__ __forceinline__ float frcp(float x) { return __builtin_amdgcn_rcpf(x); }
__device__ __forceinline__ float fsigm(float x) { return frcp(1.f + __expf(-x)); }
__device__ __forceinline__ float ftanh(float x) { return 1.f - 2.f * frcp(1.f + __expf(2.f * x)); }

// ---------------- ES scan ----------------
__global__ __launch_bounds__(256)
void es_kernel(const float* __restrict__ train, const float* __restrict__ lev_raw,
               const float* __restrict__ seas_raw, const float* __restrict__ init_seas,
               const int* __restrict__ idxs,
               float* __restrict__ levs, float* __restrict__ seas, float* __restrict__ out) {
  __shared__ float buf[256 * 12];
  __shared__ float red[256];
  const int b = threadIdx.x;
  const int ix = idxs[b];
  const float ls = 1.f / (1.f + expf(-lev_raw[ix]));
  const float ss = 1.f / (1.f + expf(-seas_raw[ix]));
#pragma unroll
  for (int k = 0; k < 12; ++k) {
    float v = expf(init_seas[ix * 12 + k]);
    buf[b * 12 + k] = v;
    seas[b * 264 + k] = v;
  }
  seas[b * 264 + 12] = buf[b * 12];
  float lev = train[b * 240] / buf[b * 12];
  levs[b * 240] = lev;
  float ld_prev = 0.f, pen_acc = 0.f;
  for (int i = 0; i < 239; ++i) {
    float x = train[b * 240 + 1 + i];
    int slot = (1 + i) % 12;
    float si = buf[b * 12 + slot];
    float nl = ls * (x / si) + (1.f - ls) * lev;
    float ld = logf(nl / lev);
    float ns = ss * (x / nl) + (1.f - ss) * si;
    buf[b * 12 + slot] = ns;
    levs[b * 240 + 1 + i] = nl;
    seas[b * 264 + 13 + i] = ns;
    if (i > 0) { float d = ld - ld_prev; pen_acc += d * d; }
    ld_prev = ld;
    lev = nl;
  }
#pragma unroll
  for (int k = 0; k < 12; ++k) seas[b * 264 + 252 + k] = seas[b * 264 + 240 + k];
  red[b] = pen_acc;
  __syncthreads();
  if (b == 0) {
    float s = 0.f;
    for (int i = 0; i < 256; ++i) s += red[i];
    out[PEN_OFF] = s / (238.f * 256.f);
  }
}

// ---------------- window prep ----------------
__global__ __launch_bounds__(256)
void prep_kernel(const float* __restrict__ train, const float* __restrict__ info_cat,
                 const float* __restrict__ val, const float* __restrict__ levs,
                 const float* __restrict__ seas, unsigned short* __restrict__ X0,
                 float* __restrict__ out) {
  const int t = blockIdx.x;   // 0..239
  const int b = threadIdx.x;  // 0..255
  alignas(16) unsigned short xr[32];
#pragma unroll
  for (int k = 0; k < 32; ++k) xr[k] = 0;
  if (t < 229) {
    const float lv = levs[b * 240 + t + 11];
#pragma unroll
    for (int k = 0; k < 12; ++k) {
      float v = train[b * 240 + t + k] / seas[b * 264 + t + k] / lv;
      xr[k] = f2bf(v);
    }
#pragma unroll
    for (int k = 0; k < 6; ++k) xr[12 + k] = f2bf(info_cat[b * 6 + k]);
  }
  uint4* dst = (uint4*)(X0 + ((size_t)t * 256 + b) * 32);
  const uint4* src = (const uint4*)xr;
  dst[0] = src[0]; dst[1] = src[1]; dst[2] = src[2]; dst[3] = src[3];
  if (t < 211) {
    const float lv = levs[b * 240 + t + 11];
    for (int j = 0; j < 18; ++j) {
      out[WOUT_OFF + ((size_t)t * 256 + b) * 18 + j] =
          train[b * 240 + 12 + t + j] / seas[b * 264 + 12 + t + j] / lv;
    }
  }
  if (t == 229) {
    for (int j = 0; j < 18; ++j) out[VAL_OFF + (size_t)b * 18 + j] = val[b * 18 + j];
  }
}

// ---------------- weight conversion to MFMA B-fragment order ----------------
struct WcvtArgs {
  const float* wih[4];
  const float* whh[4];
  const float* nlW;
  const float* scW;
  unsigned short* dst[6];  // W0..W3, WNL, WSC
};

__global__ __launch_bounds__(256)
void wcvt_kernel(WcvtArgs a) {
  int id = blockIdx.x * 256 + threadIdx.x;
  int mat;
  if (id < 36864) { mat = 0; }
  else { id -= 36864;
    if (id < 65536) mat = 1;
    else { id -= 65536;
      if (id < 65536) mat = 2;
      else { id -= 65536;
        if (id < 65536) mat = 3;
        else { id -= 65536;
          if (id < 8192) mat = 4;
          else { id -= 8192; mat = 5; if (id >= 1024) return; }
        }
      }
    }
  }
  const int NT = (mat <= 3) ? 64 : (mat == 4 ? 16 : 2);
  const int kc = id / (NT * 64);
  const int r = id % (NT * 64);
  const int tidx = r / 64;
  const int ln = r % 64;
  const int l15 = ln & 15, l4 = ln >> 4;
  union { unsigned short v[8]; uint4 u; } vals;
#pragma unroll
  for (int j = 0; j < 8; ++j) {
    int k = kc * 32 + l4 * 4 + (j & 3) + ((j >> 2) << 4);
    float v;
    if (mat <= 3) {
      int n = (tidx & 3) * 256 + (tidx >> 2) * 16 + l15;
      int kx = (mat == 0) ? 32 : 256;
      int din = (mat == 0) ? 18 : 256;
      if (k < kx) v = (k < din) ? a.wih[mat][n * din + k] : 0.f;
      else        v = a.whh[mat][n * 256 + (k - kx)];
    } else if (mat == 4) {
      int n = tidx * 16 + l15;
      v = a.nlW[n * 256 + k];
    } else {
      int n = tidx * 16 + l15;
      v = (n < 18) ? a.scW[n * 256 + k] : 0.f;
    }
    vals.v[j] = f2bf(v);
  }
  *(uint4*)(a.dst[mat] + ((size_t)(kc * NT + tidx) * 64 + ln) * 8) = vals.u;
}

// ---------------- dilated LSTM layer (persistent per-WG recurrence) ----------------
// Row layout: row = t*256 + b. A dilation-r step s covers rows [s*r*256, (s+1)*r*256).
// Each WG owns a fixed ROWS-slice of every step-block -> h/c recurrence stays in-WG.
template <int KCT, int KXC, int XSTRIDE, int MT>
__global__ __launch_bounds__(512, 2)
void lstm_kernel(const unsigned short* __restrict__ X, unsigned short* __restrict__ Y,
                 const unsigned short* __restrict__ Wf, const float* __restrict__ bih,
                 const float* __restrict__ bhh, int rate) {
  constexpr int KPAD = KCT * 32 + 8;
  constexpr int ROWS = 16 * MT;
  constexpr int WPM = 8 / MT;   // waves per M-tile
  constexpr int CW = 2 * MT;    // j-chunks (c) per wave
  constexpr int NTW = 8 * MT;   // N-tiles per wave
  __shared__ __align__(16) unsigned short A[ROWS][KPAD];

  const int tid = threadIdx.x;
  const int wv = tid >> 6;
  const int ln = tid & 63;
  const int l15 = ln & 15;
  const int l4 = ln >> 4;
  const int mt = wv / WPM;
  const int c0 = (wv % WPM) * CW;
  const int rbase = blockIdx.x * ROWS;
  const int S = NWPAD / rate;
  const int stepRows = rate * 256;

  float bias[NTW];
#pragma unroll
  for (int i = 0; i < NTW; ++i) {
    int n = (i & 3) * 256 + (c0 + (i >> 2)) * 16 + l15;
    bias[i] = bih[n] + bhh[n];
  }
  f32x4 acc[NTW];
#pragma unroll
  for (int i = 0; i < NTW; ++i) acc[i] = (f32x4){0.f, 0.f, 0.f, 0.f};
  float cst[CW][4];
#pragma unroll
  for (int c = 0; c < CW; ++c)
#pragma unroll
    for (int q = 0; q < 4; ++q) cst[c][q] = 0.f;

  // kc=0 weight fragments stay register-resident (same every step)
  bf16x8 b0[NTW];
#pragma unroll
  for (int i = 0; i < NTW; ++i)
    b0[i] = *(const bf16x8*)(Wf + (((size_t)(c0 * 4 + i)) * 64 + ln) * 8);

  // zero h-region of A
  for (int ch = tid; ch < ROWS * 32; ch += 512) {
    int m = ch >> 5, sg = ch & 31;
    *(uint4*)&A[m][KXC * 32 + sg * 8] = make_uint4(0u, 0u, 0u, 0u);
  }
  // stage x for s=0
  {
    constexpr int NC = XSTRIDE / 8;
    for (int ch = tid; ch < ROWS * NC; ch += 512) {
      int m = ch / NC, sg = ch % NC;
      *(uint4*)&A[m][sg * 8] = *(const uint4*)(X + ((size_t)rbase + m) * XSTRIDE + sg * 8);
    }
  }
  __syncthreads();

  for (int s = 0; s < S; ++s) {
    // ---- gates = [x | h_prev] @ W^T  (MFMA, K = KCT*32) ----
#pragma unroll
    for (int kc = 0; kc < KCT; ++kc) {
      union { unsigned long long u[2]; bf16x8 v; } au;
      const unsigned short* ap = &A[mt * 16 + l15][kc * 32 + l4 * 4];
      au.u[0] = *(const unsigned long long*)ap;
      au.u[1] = *(const unsigned long long*)(ap + 16);
#pragma unroll
      for (int i = 0; i < NTW; ++i) {
        bf16x8 bfr;
        if (kc == 0) bfr = b0[i];
        else bfr = *(const bf16x8*)(Wf + (((size_t)kc * 64 + c0 * 4 + i) * 64 + ln) * 8);
        acc[i] = __builtin_amdgcn_mfma_f32_16x16x32_bf16(au.v, bfr, acc[i], 0, 0, 0);
      }
    }
    // ---- pointwise LSTM cell (c-state fully register-resident) ----
    unsigned short hb[CW][4];
    const int growb = s * stepRows + rbase + mt * 16 + l4 * 4;
#pragma unroll
    for (int c = 0; c < CW; ++c) {
#pragma unroll
      for (int q = 0; q < 4; ++q) {
        float gi = acc[c * 4 + 0][q] + bias[c * 4 + 0];
        float gf = acc[c * 4 + 1][q] + bias[c * 4 + 1];
        float gc = acc[c * 4 + 2][q] + bias[c * 4 + 2];
        float go = acc[c * 4 + 3][q] + bias[c * 4 + 3];
        float iv = fsigm(gi);
        float fv = fsigm(gf);
        float cv = ftanh(gc);
        float ov = fsigm(go);
        float cn = fv * cst[c][q] + iv * cv;
        cst[c][q] = cn;
        float hv = ov * ftanh(cn);
        unsigned short hu = f2bf(hv);
        hb[c][q] = hu;
        Y[(size_t)(growb + q) * HIDN + (c0 + c) * 16 + l15] = hu;
      }
    }
#pragma unroll
    for (int i = 0; i < NTW; ++i) acc[i] = (f32x4){0.f, 0.f, 0.f, 0.f};
    __syncthreads();  // everyone done reading A this step
    // write h into A's h-region for next step
#pragma unroll
    for (int c = 0; c < CW; ++c)
#pragma unroll
      for (int q = 0; q < 4; ++q)
        A[mt * 16 + l4 * 4 + q][KXC * 32 + (c0 + c) * 16 + l15] = hb[c][q];
    // stage x for s+1
    if (s + 1 < S) {
      constexpr int NC = XSTRIDE / 8;
      const size_t gr0 = (size_t)(s + 1) * stepRows + rbase;
      for (int ch = tid; ch < ROWS * NC; ch += 512) {
        int m = ch / NC, sg = ch % NC;
        *(uint4*)&A[m][sg * 8] = *(const uint4*)(X + (gr0 + m) * XSTRIDE + sg * 8);
      }
    }
    __syncthreads();
  }
}

// ---------------- non-linear head: tanh(x@nlW^T+nlb)@scW^T+scb + epilogues ----------------
__global__ __launch_bounds__(256)
void nl_kernel(const unsigned short* __restrict__ G2, const unsigned short* __restrict__ H2,
               const unsigned short* __restrict__ Wnl, const unsigned short* __restrict__ Wsc,
               const float* __restrict__ nlb, const float* __restrict__ scb,
               const float* __restrict__ seas, const float* __restrict__ levs,
               float* __restrict__ out) {
  __shared__ __align__(16) unsigned short A[64][264];
  __shared__ __align__(16) unsigned short U[64][264];
  const int tid = threadIdx.x;
  const int wv = tid >> 6, ln = tid & 63, l15 = ln & 15, l4 = ln >> 4;
  const size_t row0 = (size_t)blockIdx.x * 64;

  for (int ch = tid; ch < 2048; ch += 256) {
    int m = ch >> 5, sg = ch & 31;
    const size_t base = (row0 + m) * HIDN + sg * 8;
    uint4 gv = *(const uint4*)(G2 + base);
    uint4 hv = *(const uint4*)(H2 + base);
    union { unsigned short v[8]; uint4 u; } r;
    const unsigned short* gs = (const unsigned short*)&gv;
    const unsigned short* hs = (const unsigned short*)&hv;
#pragma unroll
    for (int j = 0; j < 8; ++j) r.v[j] = f2bf(bf2f(gs[j]) + bf2f(hs[j]));
    *(uint4*)&A[m][sg * 8] = r.u;
  }
  __syncthreads();

  f32x4 acc[16];
#pragma unroll
  for (int i = 0; i < 16; ++i) acc[i] = (f32x4){0.f, 0.f, 0.f, 0.f};
#pragma unroll
  for (int kc = 0; kc < 8; ++kc) {
    union { unsigned long long u[2]; bf16x8 v; } au;
    const unsigned short* ap = &A[wv * 16 + l15][kc * 32 + l4 * 4];
    au.u[0] = *(const unsigned long long*)ap;
    au.u[1] = *(const unsigned long long*)(ap + 16);
#pragma unroll
    for (int i = 0; i < 16; ++i) {
      bf16x8 b = *(const bf16x8*)(Wnl + (((size_t)kc * 16 + i) * 64 + ln) * 8);
      acc[i] = __builtin_amdgcn_mfma_f32_16x16x32_bf16(au.v, b, acc[i], 0, 0, 0);
    }
  }
#pragma unroll
  for (int i = 0; i < 16; ++i) {
#pragma unroll
    for (int q = 0; q < 4; ++q) {
      float u = ftanh(acc[i][q] + nlb[i * 16 + l15]);
      U[wv * 16 + l4 * 4 + q][i * 16 + l15] = f2bf(u);
    }
  }
  __syncthreads();
  f32x4 acc2[2];
  acc2[0] = (f32x4){0.f, 0.f, 0.f, 0.f};
  acc2[1] = (f32x4){0.f, 0.f, 0.f, 0.f};
#pragma unroll
  for (int kc = 0; kc < 8; ++kc) {
    union { unsigned long long u[2]; bf16x8 v; } au;
    const unsigned short* ap = &U[wv * 16 + l15][kc * 32 + l4 * 4];
    au.u[0] = *(const unsigned long long*)ap;
    au.u[1] = *(const unsigned long long*)(ap + 16);
#pragma unroll
    for (int i = 0; i < 2; ++i) {
      bf16x8 b = *(const bf16x8*)(Wsc + (((size_t)kc * 2 + i) * 64 + ln) * 8);
      acc2[i] = __builtin_amdgcn_mfma_f32_16x16x32_bf16(au.v, b, acc2[i], 0, 0, 0);
    }
  }
#pragma unroll
  for (int i = 0; i < 2; ++i) {
#pragma unroll
    for (int q = 0; q < 4; ++q) {
      int n = i * 16 + l15;
      if (n < 18) {
        float v = acc2[i][q] + scb[n];
        size_t gr = row0 + wv * 16 + l4 * 4 + q;
        int t = (int)(gr >> 8), b = (int)(gr & 255);
        if (t < 211) out[NET_OFF + ((size_t)t * 256 + b) * 18 + n] = v;
        if (t == 228) {
          float ho = v * seas[b * 264 + 246 + n] * levs[b * 240 + 239];
          out[HO_OFF + (size_t)b * 18 + n] = ho > 0.f ? ho : 0.f;
        }
      }
    }
  }
}

// ---------------- launch ----------------
extern "C" void kernel_launch(void* const* d_in, const int* in_sizes, int n_in,
                              void* d_out, int out_size, void* d_ws, size_t ws_size,
                              hipStream_t stream) {
  (void)in_sizes; (void)n_in; (void)out_size; (void)ws_size;
  const float* Wih[4] = {(const float*)d_in[0], (const float*)d_in[4], (const float*)d_in[8], (const float*)d_in[12]};
  const float* Whh[4] = {(const float*)d_in[1], (const float*)d_in[5], (const float*)d_in[9], (const float*)d_in[13]};
  const float* bih[4] = {(const float*)d_in[2], (const float*)d_in[6], (const float*)d_in[10], (const float*)d_in[14]};
  const float* bhh[4] = {(const float*)d_in[3], (const float*)d_in[7], (const float*)d_in[11], (const float*)d_in[15]};
  const float* nlW = (const float*)d_in[16];
  const float* nlb = (const float*)d_in[17];
  const float* scW = (const float*)d_in[18];
  const float* scb = (const float*)d_in[19];
  const float* train = (const float*)d_in[20];
  const float* val = (const float*)d_in[21];
  const float* info_cat = (const float*)d_in[23];
  const float* lev_raw = (const float*)d_in[24];
  const float* seas_raw = (const float*)d_in[25];
  const float* init_seas = (const float*)d_in[26];
  const int* idxs = (const int*)d_in[27];
  float* out = (float*)d_out;
  char* ws = (char*)d_ws;

  float* levs = (float*)(ws + OFF_LEVS);
  float* seas = (float*)(ws + OFF_SEAS);
  unsigned short* X0 = (unsigned short*)(ws + OFF_X0);
  unsigned short* Y1 = (unsigned short*)(ws + OFF_Y1);
  unsigned short* Y2 = (unsigned short*)(ws + OFF_Y2);
  unsigned short* Y3 = (unsigned short*)(ws + OFF_Y3);
  unsigned short* W0 = (unsigned short*)(ws + OFF_W0);
  unsigned short* W1 = (unsigned short*)(ws + OFF_W1);
  unsigned short* W2 = (unsigned short*)(ws + OFF_W2);
  unsigned short* W3 = (unsigned short*)(ws + OFF_W3);
  unsigned short* WNL = (unsigned short*)(ws + OFF_WNL);
  unsigned short* WSC = (unsigned short*)(ws + OFF_WSC);

  WcvtArgs wa;
  for (int i = 0; i < 4; ++i) { wa.wih[i] = Wih[i]; wa.whh[i] = Whh[i]; }
  wa.nlW = nlW; wa.scW = scW;
  wa.dst[0] = W0; wa.dst[1] = W1; wa.dst[2] = W2; wa.dst[3] = W3; wa.dst[4] = WNL; wa.dst[5] = WSC;

  hipLaunchKernelGGL(wcvt_kernel, dim3(948), dim3(256), 0, stream, wa);
  hipLaunchKernelGGL(es_kernel, dim3(1), dim3(256), 0, stream,
                     train, lev_raw, seas_raw, init_seas, idxs, levs, seas, out);
  hipLaunchKernelGGL(prep_kernel, dim3(240), dim3(256), 0, stream,
                     train, info_cat, val, levs, seas, X0, out);
  hipLaunchKernelGGL((lstm_kernel<9, 1, 32, 1>),  dim3(16), dim3(512), 0, stream, X0, Y1, W0, bih[0], bhh[0], 1);
  hipLaunchKernelGGL((lstm_kernel<16, 8, 256, 1>), dim3(48), dim3(512), 0, stream, Y1, Y2, W1, bih[1], bhh[1], 3);
  hipLaunchKernelGGL((lstm_kernel<16, 8, 256, 1>), dim3(96), dim3(512), 0, stream, Y2, Y3, W2, bih[2], bhh[2], 6);
  hipLaunchKernelGGL((lstm_kernel<16, 8, 256, 2>), dim3(96), dim3(512), 0, stream, Y3, Y1, W3, bih[3], bhh[3], 12);
  hipLaunchKernelGGL(nl_kernel, dim3(916), dim3(256), 0, stream, Y1, Y2, WNL, WSC, nlb, scb, seas, levs, out);
}

// Round 6
// 3081.121 us; speedup vs baseline: 2.3274x; 2.3274x over previous
//
#include <hip/hip_runtime.h>
#include <hip/hip_bf16.h>
#include <math.h>

// ---------------- problem constants ----------------
static constexpr int HIDN = 256;
static constexpr int NWPAD = 240;          // padded window-time steps (240 % {1,3,6,12} == 0)
// out offsets (in floats)
static constexpr size_t NET_OFF  = 0;                  // 211*256*18
static constexpr size_t WOUT_OFF = 972288;             // 211*256*18
static constexpr size_t HO_OFF   = 1944576;            // 256*18
static constexpr size_t VAL_OFF  = 1949184;            // 256*18
static constexpr size_t PEN_OFF  = 1953792;            // 1
// ws offsets (bytes)
static constexpr size_t OFF_LEVS = 0;                  // 256*240*4
static constexpr size_t OFF_SEAS = 245760;             // 256*264*4
static constexpr size_t OFF_X0   = 516096;             // 61440*32*2
static constexpr size_t OFF_Y1   = 4448256;            // 61440*256*2
static constexpr size_t OFF_Y2   = 35905536;
static constexpr size_t OFF_Y3   = 67362816;
static constexpr size_t OFF_W0   = 98820096;           // 9*64*64*8*2 (combined [x|h])
static constexpr size_t OFF_W1   = 99409920;           // 16*64*64*8*2
static constexpr size_t OFF_W2   = 100458496;
static constexpr size_t OFF_W3   = 101507072;
static constexpr size_t OFF_WNL  = 102555648;          // 8*16*64*8*2
static constexpr size_t OFF_WSC  = 102686720;          // 8*2*64*8*2
static constexpr size_t OFF_GX   = 102703104;          // 3840*64*64*8 = 125,829,120 (bf16 frag)
static constexpr size_t WS_NEED_GX = OFF_GX + 125829120ull;  // 228,532,224

typedef __attribute__((ext_vector_type(8))) short bf16x8;
typedef __attribute__((ext_vector_type(4))) float f32x4;

__device__ __forceinline__ unsigned short f2bf(float f) {
  unsigned int u = __float_as_uint(f);
  unsigned int r = (u + 0x7FFFu + ((u >> 16) & 1u)) >> 16;
  return (unsigned short)r;
}
__device__ __forceinline__ float bf2f(unsigned short s) {
  return __uint_as_float(((unsigned int)s) << 16);
}
__device__ __forceinline__ float frcp(float x) { return __builtin_amdgcn_rcpf(x); }
__device__ __forceinline__ float fsigm(float x) { return frcp(1.f + __expf(-x)); }
__device__ __forceinline__ float ftanh(float x) { return 1.f - 2.f * frcp(1.f + __expf(2.f * x)); }

// ---------------- ES scan ----------------
__global__ __launch_bounds__(256)
void es_kernel(const float* __restrict__ train, const float* __restrict__ lev_raw,
               const float* __restrict__ seas_raw, const float* __restrict__ init_seas,
               const int* __restrict__ idxs,
               float* __restrict__ levs, float* __restrict__ seas, float* __restrict__ out) {
  __shared__ float buf[256 * 12];
  __shared__ float red[256];
  const int b = threadIdx.x;
  const int ix = idxs[b];
  const float ls = 1.f / (1.f + expf(-lev_raw[ix]));
  const float ss = 1.f / (1.f + expf(-seas_raw[ix]));
#pragma unroll
  for (int k = 0; k < 12; ++k) {
    float v = expf(init_seas[ix * 12 + k]);
    buf[b * 12 + k] = v;
    seas[b * 264 + k] = v;
  }
  seas[b * 264 + 12] = buf[b * 12];
  float lev = train[b * 240] / buf[b * 12];
  levs[b * 240] = lev;
  float ld_prev = 0.f, pen_acc = 0.f;
  for (int i = 0; i < 239; ++i) {
    float x = train[b * 240 + 1 + i];
    int slot = (1 + i) % 12;
    float si = buf[b * 12 + slot];
    float nl = ls * (x / si) + (1.f - ls) * lev;
    float ld = logf(nl / lev);
    float ns = ss * (x / nl) + (1.f - ss) * si;
    buf[b * 12 + slot] = ns;
    levs[b * 240 + 1 + i] = nl;
    seas[b * 264 + 13 + i] = ns;
    if (i > 0) { float d = ld - ld_prev; pen_acc += d * d; }
    ld_prev = ld;
    lev = nl;
  }
#pragma unroll
  for (int k = 0; k < 12; ++k) seas[b * 264 + 252 + k] = seas[b * 264 + 240 + k];
  red[b] = pen_acc;
  __syncthreads();
  if (b == 0) {
    float s = 0.f;
    for (int i = 0; i < 256; ++i) s += red[i];
    out[PEN_OFF] = s / (238.f * 256.f);
  }
}

// ---------------- window prep ----------------
__global__ __launch_bounds__(256)
void prep_kernel(const float* __restrict__ train, const float* __restrict__ info_cat,
                 const float* __restrict__ val, const float* __restrict__ levs,
                 const float* __restrict__ seas, unsigned short* __restrict__ X0,
                 float* __restrict__ out) {
  const int t = blockIdx.x;   // 0..239
  const int b = threadIdx.x;  // 0..255
  alignas(16) unsigned short xr[32];
#pragma unroll
  for (int k = 0; k < 32; ++k) xr[k] = 0;
  if (t < 229) {
    const float lv = levs[b * 240 + t + 11];
#pragma unroll
    for (int k = 0; k < 12; ++k) {
      float v = train[b * 240 + t + k] / seas[b * 264 + t + k] / lv;
      xr[k] = f2bf(v);
    }
#pragma unroll
    for (int k = 0; k < 6; ++k) xr[12 + k] = f2bf(info_cat[b * 6 + k]);
  }
  uint4* dst = (uint4*)(X0 + ((size_t)t * 256 + b) * 32);
  const uint4* src = (const uint4*)xr;
  dst[0] = src[0]; dst[1] = src[1]; dst[2] = src[2]; dst[3] = src[3];
  if (t < 211) {
    const float lv = levs[b * 240 + t + 11];
    for (int j = 0; j < 18; ++j) {
      out[WOUT_OFF + ((size_t)t * 256 + b) * 18 + j] =
          train[b * 240 + 12 + t + j] / seas[b * 264 + 12 + t + j] / lv;
    }
  }
  if (t == 229) {
    for (int j = 0; j < 18; ++j) out[VAL_OFF + (size_t)b * 18 + j] = val[b * 18 + j];
  }
}

// ---------------- weight conversion to MFMA B-fragment order (combined [x|h]) ----------------
struct WcvtArgs {
  const float* wih[4];
  const float* whh[4];
  const float* nlW;
  const float* scW;
  unsigned short* dst[6];  // W0..W3, WNL, WSC
};

__global__ __launch_bounds__(256)
void wcvt_kernel(WcvtArgs a) {
  int id = blockIdx.x * 256 + threadIdx.x;
  int mat;
  if (id < 36864) { mat = 0; }
  else { id -= 36864;
    if (id < 65536) mat = 1;
    else { id -= 65536;
      if (id < 65536) mat = 2;
      else { id -= 65536;
        if (id < 65536) mat = 3;
        else { id -= 65536;
          if (id < 8192) mat = 4;
          else { id -= 8192; mat = 5; if (id >= 1024) return; }
        }
      }
    }
  }
  const int NT = (mat <= 3) ? 64 : (mat == 4 ? 16 : 2);
  const int kc = id / (NT * 64);
  const int r = id % (NT * 64);
  const int tidx = r / 64;
  const int ln = r % 64;
  const int l15 = ln & 15, l4 = ln >> 4;
  union { unsigned short v[8]; uint4 u; } vals;
#pragma unroll
  for (int j = 0; j < 8; ++j) {
    int k = kc * 32 + l4 * 4 + (j & 3) + ((j >> 2) << 4);
    float v;
    if (mat <= 3) {
      int n = (tidx & 3) * 256 + (tidx >> 2) * 16 + l15;
      int kx = (mat == 0) ? 32 : 256;
      int din = (mat == 0) ? 18 : 256;
      if (k < kx) v = (k < din) ? a.wih[mat][n * din + k] : 0.f;
      else        v = a.whh[mat][n * 256 + (k - kx)];
    } else if (mat == 4) {
      int n = tidx * 16 + l15;
      v = a.nlW[n * 256 + k];
    } else {
      int n = tidx * 16 + l15;
      v = (n < 18) ? a.scW[n * 256 + k] : 0.f;
    }
    vals.v[j] = f2bf(v);
  }
  *(uint4*)(a.dst[mat] + ((size_t)(kc * NT + tidx) * 64 + ln) * 8) = vals.u;
}

// ---------------- Gx = x @ Wx^T + bih + bhh (per layer, frag-layout output) ----------------
// KCX: #k-groups of the x-part in the combined W layout (L0:1, L1-3:8); XSTR: x row stride.
template <int KCX, int XSTR>
__global__ __launch_bounds__(512)
void gx_kernel(const unsigned short* __restrict__ X, const unsigned short* __restrict__ Wc,
               const float* __restrict__ bih, const float* __restrict__ bhh,
               unsigned short* __restrict__ GX) {
  constexpr int AP = XSTR + 8;
  __shared__ __align__(16) unsigned short A[128][AP];
  __shared__ __align__(16) unsigned short WB[16 * 64 * 8];
  const int tid = threadIdx.x;
  const int wv = tid >> 6, ln = tid & 63, l15 = ln & 15, l4 = ln >> 4;
  const int rg = blockIdx.x >> 2;   // 0..479  (128-row slab)
  const int cg = blockIdx.x & 3;    // 0..3    (16-tile column group)
  const size_t row0 = (size_t)rg * 128;
  {
    constexpr int NC = XSTR / 8;
    for (int ch = tid; ch < 128 * NC; ch += 512) {
      int m = ch / NC, sg = ch % NC;
      *(uint4*)&A[m][sg * 8] = *(const uint4*)(X + (row0 + m) * XSTR + sg * 8);
    }
  }
  f32x4 acc[16];
#pragma unroll
  for (int i = 0; i < 16; ++i) acc[i] = (f32x4){0.f, 0.f, 0.f, 0.f};
  for (int kc = 0; kc < KCX; ++kc) {
    __syncthreads();
    for (int ch = tid; ch < 1024; ch += 512) {
      int t8 = ch >> 6, l = ch & 63;
      *(uint4*)&WB[(t8 * 64 + l) * 8] =
          *(const uint4*)(Wc + (((size_t)kc * 64 + cg * 16 + t8) * 64 + l) * 8);
    }
    __syncthreads();
    union { unsigned long long u[2]; bf16x8 v; } au;
    const unsigned short* ap = &A[wv * 16 + l15][kc * 32 + l4 * 4];
    au.u[0] = *(const unsigned long long*)ap;
    au.u[1] = *(const unsigned long long*)(ap + 16);
#pragma unroll
    for (int i = 0; i < 16; ++i) {
      bf16x8 b = *(const bf16x8*)&WB[(i * 64 + ln) * 8];
      acc[i] = __builtin_amdgcn_mfma_f32_16x16x32_bf16(au.v, b, acc[i], 0, 0, 0);
    }
  }
  const int rt = rg * 8 + wv;
#pragma unroll
  for (int i = 0; i < 16; ++i) {
    int tg = cg * 16 + i;
    int n = (tg & 3) * 256 + (tg >> 2) * 16 + l15;
    float bz = bih[n] + bhh[n];
    unsigned int lo = (unsigned int)f2bf(acc[i][0] + bz) | ((unsigned int)f2bf(acc[i][1] + bz) << 16);
    unsigned int hi = (unsigned int)f2bf(acc[i][2] + bz) | ((unsigned int)f2bf(acc[i][3] + bz) << 16);
    *(uint2*)(GX + ((size_t)(rt * 64 + tg) * 64 + ln) * 4) = make_uint2(lo, hi);
  }
}

// ---------------- fast LSTM recurrence: gates = Gx + h @ Wh^T ----------------
// 1024 threads = 16 waves (4/SIMD -> 128-VGPR cap). Wave wv owns col-chunk wv: tiles wv*4+g.
// Hybrid weight residency under the cap: kc 0..3 register-resident (64 VGPR), kc 4..7
// streamed per step via a single 4-frag buffer (16 VGPR), issue-before-use; TLP (4 waves/SIMD)
// hides residual latency. Gx loaded at step start, folded in after the K-loop.
// KXC = k-group offset of the h-part in combined W (L0:1, L1-3:8).
template <int KXC>
__global__ __launch_bounds__(1024)
void lstm_fast(const unsigned short* __restrict__ GX, unsigned short* __restrict__ Y,
               const unsigned short* __restrict__ Wc, int S, int stepRows) {
  __shared__ __align__(16) unsigned short A[16][264];
  const int tid = threadIdx.x, wv = tid >> 6, ln = tid & 63, l15 = ln & 15, l4 = ln >> 4;
  const int bid = blockIdx.x;
  // zero h buffer
  for (int ch = tid; ch < 528; ch += 1024) {
    int m = ch / 33, sg = ch % 33;
    *(uint4*)&A[m][sg * 8] = make_uint4(0u, 0u, 0u, 0u);
  }
  const int rtStep = stepRows >> 4;
  float cst[4] = {0.f, 0.f, 0.f, 0.f};

  // per-thread weight base: tile (wv*4+g), k-group (kc+KXC); frag(kc,g) = base + kc*32768 + g*512
  const unsigned short* wbase = Wc + (((size_t)KXC * 64 + wv * 4) * 64 + ln) * 8;
  bf16x8 wres[4][4];
#pragma unroll
  for (int kc = 0; kc < 4; ++kc)
#pragma unroll
    for (int g = 0; g < 4; ++g)
      wres[kc][g] = *(const bf16x8*)(wbase + (size_t)kc * 32768 + (size_t)g * 512);

  const unsigned short* gxb = GX + ((size_t)(wv * 4) * 64 + ln) * 4;
  __syncthreads();

  bf16x8 wbuf[4];
  for (int s = 0; s < S; ++s) {
    const int rt = s * rtStep + bid;
    const unsigned short* gxp = gxb + (size_t)rt * 16384;
    uint2 gxn[4];
#pragma unroll
    for (int g = 0; g < 4; ++g) gxn[g] = *(const uint2*)(gxp + g * 256);
    // issue stream loads for kc=4 (land under the resident-kc MFMAs)
#pragma unroll
    for (int g = 0; g < 4; ++g)
      wbuf[g] = *(const bf16x8*)(wbase + (size_t)4 * 32768 + (size_t)g * 512);

    f32x4 acc[4];
#pragma unroll
    for (int g = 0; g < 4; ++g) acc[g] = (f32x4){0.f, 0.f, 0.f, 0.f};
#pragma unroll
    for (int kc = 0; kc < 4; ++kc) {
      union { unsigned long long u[2]; bf16x8 v; } au;
      const unsigned short* ap = &A[l15][kc * 32 + l4 * 4];
      au.u[0] = *(const unsigned long long*)ap;
      au.u[1] = *(const unsigned long long*)(ap + 16);
#pragma unroll
      for (int g = 0; g < 4; ++g)
        acc[g] = __builtin_amdgcn_mfma_f32_16x16x32_bf16(au.v, wres[kc][g], acc[g], 0, 0, 0);
    }
#pragma unroll
    for (int kc = 4; kc < 8; ++kc) {
      union { unsigned long long u[2]; bf16x8 v; } au;
      const unsigned short* ap = &A[l15][kc * 32 + l4 * 4];
      au.u[0] = *(const unsigned long long*)ap;
      au.u[1] = *(const unsigned long long*)(ap + 16);
#pragma unroll
      for (int g = 0; g < 4; ++g)
        acc[g] = __builtin_amdgcn_mfma_f32_16x16x32_bf16(au.v, wbuf[g], acc[g], 0, 0, 0);
      if (kc < 7) {
        // overwrite wbuf after the MFMAs consumed it (WAR-safe in-order issue)
#pragma unroll
        for (int g = 0; g < 4; ++g)
          wbuf[g] = *(const bf16x8*)(wbase + (size_t)(kc + 1) * 32768 + (size_t)g * 512);
      }
    }
    // fold in Gx (loads issued at step start; latency hidden under the K-loop)
#pragma unroll
    for (int g = 0; g < 4; ++g) {
      acc[g][0] += bf2f((unsigned short)(gxn[g].x & 0xffff));
      acc[g][1] += bf2f((unsigned short)(gxn[g].x >> 16));
      acc[g][2] += bf2f((unsigned short)(gxn[g].y & 0xffff));
      acc[g][3] += bf2f((unsigned short)(gxn[g].y >> 16));
    }
    unsigned short hb[4];
    const int growb = s * stepRows + bid * 16 + l4 * 4;
#pragma unroll
    for (int q = 0; q < 4; ++q) {
      float iv = fsigm(acc[0][q]);
      float fv = fsigm(acc[1][q]);
      float cv = ftanh(acc[2][q]);
      float ov = fsigm(acc[3][q]);
      float cn = fv * cst[q] + iv * cv;
      cst[q] = cn;
      float hv = ov * ftanh(cn);
      unsigned short hu = f2bf(hv);
      hb[q] = hu;
      Y[(size_t)(growb + q) * HIDN + wv * 16 + l15] = hu;
    }
    __syncthreads();   // all MFMA reads of A done
#pragma unroll
    for (int q = 0; q < 4; ++q)
      A[l4 * 4 + q][wv * 16 + l15] = hb[q];
    __syncthreads();   // h ready for next step
  }
}

// ---------------- legacy dilated LSTM layer (fallback when ws too small for Gx) ----------------
template <int KCT, int KXC, int XSTRIDE, int MT>
__global__ __launch_bounds__(512, 2)
void lstm_kernel(const unsigned short* __restrict__ X, unsigned short* __restrict__ Y,
                 const unsigned short* __restrict__ Wf, const float* __restrict__ bih,
                 const float* __restrict__ bhh, int rate) {
  constexpr int KPAD = KCT * 32 + 8;
  constexpr int ROWS = 16 * MT;
  constexpr int WPM = 8 / MT;
  constexpr int CW = 2 * MT;
  constexpr int NTW = 8 * MT;
  __shared__ __align__(16) unsigned short A[ROWS][KPAD];

  const int tid = threadIdx.x;
  const int wv = tid >> 6;
  const int ln = tid & 63;
  const int l15 = ln & 15;
  const int l4 = ln >> 4;
  const int mt = wv / WPM;
  const int c0 = (wv % WPM) * CW;
  const int rbase = blockIdx.x * ROWS;
  const int S = NWPAD / rate;
  const int stepRows = rate * 256;

  float bias[NTW];
#pragma unroll
  for (int i = 0; i < NTW; ++i) {
    int n = (i & 3) * 256 + (c0 + (i >> 2)) * 16 + l15;
    bias[i] = bih[n] + bhh[n];
  }
  f32x4 acc[NTW];
#pragma unroll
  for (int i = 0; i < NTW; ++i) acc[i] = (f32x4){0.f, 0.f, 0.f, 0.f};
  float cst[CW][4];
#pragma unroll
  for (int c = 0; c < CW; ++c)
#pragma unroll
    for (int q = 0; q < 4; ++q) cst[c][q] = 0.f;

  bf16x8 b0[NTW];
#pragma unroll
  for (int i = 0; i < NTW; ++i)
    b0[i] = *(const bf16x8*)(Wf + (((size_t)(c0 * 4 + i)) * 64 + ln) * 8);

  for (int ch = tid; ch < ROWS * 32; ch += 512) {
    int m = ch >> 5, sg = ch & 31;
    *(uint4*)&A[m][KXC * 32 + sg * 8] = make_uint4(0u, 0u, 0u, 0u);
  }
  {
    constexpr int NC = XSTRIDE / 8;
    for (int ch = tid; ch < ROWS * NC; ch += 512) {
      int m = ch / NC, sg = ch % NC;
      *(uint4*)&A[m][sg * 8] = *(const uint4*)(X + ((size_t)rbase + m) * XSTRIDE + sg * 8);
    }
  }
  __syncthreads();

  for (int s = 0; s < S; ++s) {
#pragma unroll
    for (int kc = 0; kc < KCT; ++kc) {
      union { unsigned long long u[2]; bf16x8 v; } au;
      const unsigned short* ap = &A[mt * 16 + l15][kc * 32 + l4 * 4];
      au.u[0] = *(const unsigned long long*)ap;
      au.u[1] = *(const unsigned long long*)(ap + 16);
#pragma unroll
      for (int i = 0; i < NTW; ++i) {
        bf16x8 bfr;
        if (kc == 0) bfr = b0[i];
        else bfr = *(const bf16x8*)(Wf + (((size_t)kc * 64 + c0 * 4 + i) * 64 + ln) * 8);
        acc[i] = __builtin_amdgcn_mfma_f32_16x16x32_bf16(au.v, bfr, acc[i], 0, 0, 0);
      }
    }
    unsigned short hb[CW][4];
    const int growb = s * stepRows + rbase + mt * 16 + l4 * 4;
#pragma unroll
    for (int c = 0; c < CW; ++c) {
#pragma unroll
      for (int q = 0; q < 4; ++q) {
        float gi = acc[c * 4 + 0][q] + bias[c * 4 + 0];
        float gf = acc[c * 4 + 1][q] + bias[c * 4 + 1];
        float gc = acc[c * 4 + 2][q] + bias[c * 4 + 2];
        float go = acc[c * 4 + 3][q] + bias[c * 4 + 3];
        float iv = fsigm(gi);
        float fv = fsigm(gf);
        float cv = ftanh(gc);
        float ov = fsigm(go);
        float cn = fv * cst[c][q] + iv * cv;
        cst[c][q] = cn;
        float hv = ov * ftanh(cn);
        unsigned short hu = f2bf(hv);
        hb[c][q] = hu;
        Y[(size_t)(growb + q) * HIDN + (c0 + c) * 16 + l15] = hu;
      }
    }
#pragma unroll
    for (int i = 0; i < NTW; ++i) acc[i] = (f32x4){0.f, 0.f, 0.f, 0.f};
    __syncthreads();
#pragma unroll
    for (int c = 0; c < CW; ++c)
#pragma unroll
      for (int q = 0; q < 4; ++q)
        A[mt * 16 + l4 * 4 + q][KXC * 32 + (c0 + c) * 16 + l15] = hb[c][q];
    if (s + 1 < S) {
      constexpr int NC = XSTRIDE / 8;
      const size_t gr0 = (size_t)(s + 1) * stepRows + rbase;
      for (int ch = tid; ch < ROWS * NC; ch += 512) {
        int m = ch / NC, sg = ch % NC;
        *(uint4*)&A[m][sg * 8] = *(const uint4*)(X + (gr0 + m) * XSTRIDE + sg * 8);
      }
    }
    __syncthreads();
  }
}

// ---------------- non-linear head: tanh(x@nlW^T+nlb)@scW^T+scb + epilogues ----------------
__global__ __launch_bounds__(256)
void nl_kernel(const unsigned short* __restrict__ G2, const unsigned short* __restrict__ H2,
               const unsigned short* __restrict__ Wnl, const unsigned short* __restrict__ Wsc,
               const float* __restrict__ nlb, const float* __restrict__ scb,
               const float* __restrict__ seas, const float* __restrict__ levs,
               float* __restrict__ out) {
  __shared__ __align__(16) unsigned short A[64][264];
  __shared__ __align__(16) unsigned short U[64][264];
  const int tid = threadIdx.x;
  const int wv = tid >> 6, ln = tid & 63, l15 = ln & 15, l4 = ln >> 4;
  const size_t row0 = (size_t)blockIdx.x * 64;

  for (int ch = tid; ch < 2048; ch += 256) {
    int m = ch >> 5, sg = ch & 31;
    const size_t base = (row0 + m) * HIDN + sg * 8;
    uint4 gv = *(const uint4*)(G2 + base);
    uint4 hv = *(const uint4*)(H2 + base);
    union { unsigned short v[8]; uint4 u; } r;
    const unsigned short* gs = (const unsigned short*)&gv;
    const unsigned short* hs = (const unsigned short*)&hv;
#pragma unroll
    for (int j = 0; j < 8; ++j) r.v[j] = f2bf(bf2f(gs[j]) + bf2f(hs[j]));
    *(uint4*)&A[m][sg * 8] = r.u;
  }
  __syncthreads();

  f32x4 acc[16];
#pragma unroll
  for (int i = 0; i < 16; ++i) acc[i] = (f32x4){0.f, 0.f, 0.f, 0.f};
#pragma unroll
  for (int kc = 0; kc < 8; ++kc) {
    union { unsigned long long u[2]; bf16x8 v; } au;
    const unsigned short* ap = &A[wv * 16 + l15][kc * 32 + l4 * 4];
    au.u[0] = *(const unsigned long long*)ap;
    au.u[1] = *(const unsigned long long*)(ap + 16);
#pragma unroll
    for (int i = 0; i < 16; ++i) {
      bf16x8 b = *(const bf16x8*)(Wnl + (((size_t)kc * 16 + i) * 64 + ln) * 8);
      acc[i] = __builtin_amdgcn_mfma_f32_16x16x32_bf16(au.v, b, acc[i], 0, 0, 0);
    }
  }
#pragma unroll
  for (int i = 0; i < 16; ++i) {
#pragma unroll
    for (int q = 0; q < 4; ++q) {
      float u = ftanh(acc[i][q] + nlb[i * 16 + l15]);
      U[wv * 16 + l4 * 4 + q][i * 16 + l15] = f2bf(u);
    }
  }
  __syncthreads();
  f32x4 acc2[2];
  acc2[0] = (f32x4){0.f, 0.f, 0.f, 0.f};
  acc2[1] = (f32x4){0.f, 0.f, 0.f, 0.f};
#pragma unroll
  for (int kc = 0; kc < 8; ++kc) {
    union { unsigned long long u[2]; bf16x8 v; } au;
    const unsigned short* ap = &U[wv * 16 + l15][kc * 32 + l4 * 4];
    au.u[0] = *(const unsigned long long*)ap;
    au.u[1] = *(const unsigned long long*)(ap + 16);
#pragma unroll
    for (int i = 0; i < 2; ++i) {
      bf16x8 b = *(const bf16x8*)(Wsc + (((size_t)kc * 2 + i) * 64 + ln) * 8);
      acc2[i] = __builtin_amdgcn_mfma_f32_16x16x32_bf16(au.v, b, acc2[i], 0, 0, 0);
    }
  }
#pragma unroll
  for (int i = 0; i < 2; ++i) {
#pragma unroll
    for (int q = 0; q < 4; ++q) {
      int n = i * 16 + l15;
      if (n < 18) {
        float v = acc2[i][q] + scb[n];
        size_t gr = row0 + wv * 16 + l4 * 4 + q;
        int t = (int)(gr >> 8), b = (int)(gr & 255);
        if (t < 211) out[NET_OFF + ((size_t)t * 256 + b) * 18 + n] = v;
        if (t == 228) {
          float ho = v * seas[b * 264 + 246 + n] * levs[b * 240 + 239];
          out[HO_OFF + (size_t)b * 18 + n] = ho > 0.f ? ho : 0.f;
        }
      }
    }
  }
}

// ---------------- launch ----------------
extern "C" void kernel_launch(void* const* d_in, const int* in_sizes, int n_in,
                              void* d_out, int out_size, void* d_ws, size_t ws_size,
                              hipStream_t stream) {
  (void)in_sizes; (void)n_in; (void)out_size;
  const float* Wih[4] = {(const float*)d_in[0], (const float*)d_in[4], (const float*)d_in[8], (const float*)d_in[12]};
  const float* Whh[4] = {(const float*)d_in[1], (const float*)d_in[5], (const float*)d_in[9], (const float*)d_in[13]};
  const float* bih[4] = {(const float*)d_in[2], (const float*)d_in[6], (const float*)d_in[10], (const float*)d_in[14]};
  const float* bhh[4] = {(const float*)d_in[3], (const float*)d_in[7], (const float*)d_in[11], (const float*)d_in[15]};
  const float* nlW = (const float*)d_in[16];
  const float* nlb = (const float*)d_in[17];
  const float* scW = (const float*)d_in[18];
  const float* scb = (const float*)d_in[19];
  const float* train = (const float*)d_in[20];
  const float* val = (const float*)d_in[21];
  const float* info_cat = (const float*)d_in[23];
  const float* lev_raw = (const float*)d_in[24];
  const float* seas_raw = (const float*)d_in[25];
  const float* init_seas = (const float*)d_in[26];
  const int* idxs = (const int*)d_in[27];
  float* out = (float*)d_out;
  char* ws = (char*)d_ws;

  float* levs = (float*)(ws + OFF_LEVS);
  float* seas = (float*)(ws + OFF_SEAS);
  unsigned short* X0 = (unsigned short*)(ws + OFF_X0);
  unsigned short* Y1 = (unsigned short*)(ws + OFF_Y1);
  unsigned short* Y2 = (unsigned short*)(ws + OFF_Y2);
  unsigned short* Y3 = (unsigned short*)(ws + OFF_Y3);
  unsigned short* W0 = (unsigned short*)(ws + OFF_W0);
  unsigned short* W1 = (unsigned short*)(ws + OFF_W1);
  unsigned short* W2 = (unsigned short*)(ws + OFF_W2);
  unsigned short* W3 = (unsigned short*)(ws + OFF_W3);
  unsigned short* WNL = (unsigned short*)(ws + OFF_WNL);
  unsigned short* WSC = (unsigned short*)(ws + OFF_WSC);
  unsigned short* GX = (unsigned short*)(ws + OFF_GX);

  WcvtArgs wa;
  for (int i = 0; i < 4; ++i) { wa.wih[i] = Wih[i]; wa.whh[i] = Whh[i]; }
  wa.nlW = nlW; wa.scW = scW;
  wa.dst[0] = W0; wa.dst[1] = W1; wa.dst[2] = W2; wa.dst[3] = W3; wa.dst[4] = WNL; wa.dst[5] = WSC;

  hipLaunchKernelGGL(wcvt_kernel, dim3(948), dim3(256), 0, stream, wa);
  hipLaunchKernelGGL(es_kernel, dim3(1), dim3(256), 0, stream,
                     train, lev_raw, seas_raw, init_seas, idxs, levs, seas, out);
  hipLaunchKernelGGL(prep_kernel, dim3(240), dim3(256), 0, stream,
                     train, info_cat, val, levs, seas, X0, out);

  if (ws_size >= WS_NEED_GX) {
    // Gx-precompute path: recurrent step is h-only K=256; hybrid VGPR-resident/streamed Wh
    hipLaunchKernelGGL((gx_kernel<1, 32>), dim3(1920), dim3(512), 0, stream, X0, W0, bih[0], bhh[0], GX);
    hipLaunchKernelGGL((lstm_fast<1>), dim3(16), dim3(1024), 0, stream, GX, Y1, W0, 240, 256);
    hipLaunchKernelGGL((gx_kernel<8, 256>), dim3(1920), dim3(512), 0, stream, Y1, W1, bih[1], bhh[1], GX);
    hipLaunchKernelGGL((lstm_fast<8>), dim3(48), dim3(1024), 0, stream, GX, Y2, W1, 80, 768);
    hipLaunchKernelGGL((gx_kernel<8, 256>), dim3(1920), dim3(512), 0, stream, Y2, W2, bih[2], bhh[2], GX);
    hipLaunchKernelGGL((lstm_fast<8>), dim3(96), dim3(1024), 0, stream, GX, Y3, W2, 40, 1536);
    hipLaunchKernelGGL((gx_kernel<8, 256>), dim3(1920), dim3(512), 0, stream, Y3, W3, bih[3], bhh[3], GX);
    hipLaunchKernelGGL((lstm_fast<8>), dim3(192), dim3(1024), 0, stream, GX, Y1, W3, 20, 3072);
  } else {
    // fallback: proven round-3 path
    hipLaunchKernelGGL((lstm_kernel<9, 1, 32, 1>),  dim3(16), dim3(512), 0, stream, X0, Y1, W0, bih[0], bhh[0], 1);
    hipLaunchKernelGGL((lstm_kernel<16, 8, 256, 1>), dim3(48), dim3(512), 0, stream, Y1, Y2, W1, bih[1], bhh[1], 3);
    hipLaunchKernelGGL((lstm_kernel<16, 8, 256, 1>), dim3(96), dim3(512), 0, stream, Y2, Y3, W2, bih[2], bhh[2], 6);
    hipLaunchKernelGGL((lstm_kernel<16, 8, 256, 2>), dim3(96), dim3(512), 0, stream, Y3, Y1, W3, bih[3], bhh[3], 12);
  }
  hipLaunchKernelGGL(nl_kernel, dim3(916), dim3(256), 0, stream, Y1, Y2, WNL, WSC, nlb, scb, seas, levs, out);
}